// Round 9
// baseline (1129.779 us; speedup 1.0000x reference)
//
#include <hip/hip_runtime.h>

#define N_NODES 20000
#define N_EDGES 320000
#define CDIM    256
#define BE      1024
#define NBLK    313      // ceil(N_EDGES/BE)
#define NBN     20       // ceil(N_NODES/BE)
#define REG     256      // edges per stager-wave region
#define NREG    15       // stager waves (waves 1..15)
#define CH      (REG*NREG)                     // 3840 edges per chunk
#define NCH     ((N_EDGES + CH - 1) / CH)      // 84

#define OFF_X   0
#define OFF_EI  (N_NODES*CDIM)                 // 5120000
#define OFF_CL  (OFF_EI + 2*N_EDGES)           // 5760000
#define OFF_B   (OFF_CL + N_NODES)             // 5780000
#define OFF_NC  (OFF_B + N_NODES)              // 5800000

// ---------- XLA CPU tanh: rational approximation, plain mul/add f32 ----------
__device__ __forceinline__ float xla_tanh(float x) {
  float ax = fabsf(x);
  float xc = fminf(fmaxf(x, -9.0f), 9.0f);
  float x2 = __fmul_rn(xc, xc);
  float p = -2.76076847742355e-16f;
  p = __fadd_rn(__fmul_rn(p, x2), 2.00018790482477e-13f);
  p = __fadd_rn(__fmul_rn(p, x2), -8.60467152213735e-11f);
  p = __fadd_rn(__fmul_rn(p, x2), 5.12229709037114e-08f);
  p = __fadd_rn(__fmul_rn(p, x2), 1.48572235717979e-05f);
  p = __fadd_rn(__fmul_rn(p, x2), 6.37261928875436e-04f);
  p = __fadd_rn(__fmul_rn(p, x2), 4.89352455891786e-03f);
  float num = __fmul_rn(xc, p);
  float q = 1.19825839466702e-06f;
  q = __fadd_rn(__fmul_rn(q, x2), 1.18534705686654e-04f);
  q = __fadd_rn(__fmul_rn(q, x2), 2.26843463243900e-03f);
  q = __fadd_rn(__fmul_rn(q, x2), 4.89352518554385e-03f);
  float r = num / q;   // correctly-rounded f32 divide
  return (ax < 0.0004f) ? x : r;
}

// ---------- K0: per-node partial dots, sequential-k mul+add chain ----------
__global__ void k_node_dots(const float* __restrict__ x, const float* __restrict__ w,
                            float* __restrict__ p1, float* __restrict__ p2) {
  __shared__ float sw[2*CDIM];
  for (int i = threadIdx.x; i < 2*CDIM; i += blockDim.x) sw[i] = w[i];
  __syncthreads();
  int n = blockIdx.x * blockDim.x + threadIdx.x;
  if (n >= N_NODES) return;
  const float* row = x + (size_t)n * CDIM;
  float a1 = 0.f, a2 = 0.f;
  for (int k = 0; k < CDIM; ++k) {
    float xv = row[k];
    a1 = __fadd_rn(a1, __fmul_rn(xv, sw[k]));
    a2 = __fadd_rn(a2, __fmul_rn(xv, sw[CDIM + k]));
  }
  p1[n] = a1; p2[n] = a2;
}

// ---------- K1: edge scores + sort keys ----------
__global__ void k_edge_scores(const int* __restrict__ ei, const float* __restrict__ p1,
                              const float* __restrict__ p2, const float* __restrict__ lb,
                              float* __restrict__ e, unsigned* __restrict__ keyA,
                              int* __restrict__ payA) {
  int i = blockIdx.x * blockDim.x + threadIdx.x;
  if (i >= N_EDGES) return;
  int s = ei[i], d = ei[N_EDGES + i];
  float z = __fadd_rn(__fadd_rn(p1[s], p2[d]), lb[0]);
  float ev = __fadd_rn(xla_tanh(z), 0.5f);
  e[i] = ev;
  unsigned u = __float_as_uint(ev);
  u = (u >> 31) ? ~u : (u | 0x80000000u);   // ascending-order bits of e
  keyA[i] = ~u;                              // ascending key == descending e; ties stable by idx
  payA[i] = i;
}

// ---------- radix sort (stable LSD, 4x8 bits) ----------
__global__ void k_radix_hist(const unsigned* __restrict__ key, int n, int shift,
                             unsigned* __restrict__ hist) {
  __shared__ unsigned h[256];
  int t = threadIdx.x;
  h[t] = 0;
  __syncthreads();
  int base = blockIdx.x * BE;
  for (int j = t; j < BE; j += 256) {
    int idx = base + j;
    if (idx < n) atomicAdd(&h[(key[idx] >> shift) & 255u], 1u);
  }
  __syncthreads();
  hist[t * NBLK + blockIdx.x] = h[t];
}

__global__ void k_radix_scan(unsigned* __restrict__ hist) {
  __shared__ unsigned sums[256];
  int t = threadIdx.x;
  unsigned rs = 0;
  for (int b = 0; b < NBLK; ++b) rs += hist[t * NBLK + b];
  sums[t] = rs;
  __syncthreads();
  for (int off = 1; off < 256; off <<= 1) {
    unsigned u2 = (t >= off) ? sums[t - off] : 0u;
    __syncthreads();
    sums[t] += u2;
    __syncthreads();
  }
  unsigned run = sums[t] - rs;   // exclusive base for bin t
  for (int b = 0; b < NBLK; ++b) {
    unsigned tmp = hist[t * NBLK + b];
    hist[t * NBLK + b] = run;
    run += tmp;
  }
}

__global__ void k_radix_scatter(const unsigned* __restrict__ key, const int* __restrict__ pay,
                                int n, int shift, const unsigned* __restrict__ hist,
                                unsigned* __restrict__ keyo, int* __restrict__ payo) {
  __shared__ unsigned mask[256][8];
  __shared__ unsigned rbase[256];
  int t = threadIdx.x;
  rbase[t] = hist[t * NBLK + blockIdx.x];
  __syncthreads();
  int base = blockIdx.x * BE;
  for (int tile = 0; tile < BE / 256; ++tile) {
    for (int wq = 0; wq < 8; ++wq) mask[t][wq] = 0u;
    __syncthreads();
    int idx = base + tile * 256 + t;
    unsigned k = 0; int bin = 0; int valid = (idx < n);
    if (valid) {
      k = key[idx];
      bin = (k >> shift) & 255;
      atomicOr(&mask[bin][t >> 5], 1u << (t & 31));
    }
    __syncthreads();
    if (valid) {
      int w = t >> 5;
      unsigned r = 0;
      for (int w2 = 0; w2 < w; ++w2) r += __popc(mask[bin][w2]);
      r += __popc(mask[bin][w] & ((1u << (t & 31)) - 1u));
      unsigned pos = rbase[bin] + r;
      keyo[pos] = k;
      payo[pos] = pay[idx];
    }
    __syncthreads();
    unsigned c = 0;
    for (int wq = 0; wq < 8; ++wq) c += __popc(mask[t][wq]);
    rbase[t] += c;
    __syncthreads();
  }
}

// ---------- K14: gather sorted endpoints + packed worklist + zero take ----------
// packed entry: (p << 30) | (s << 15) | d   with p = sorted position (= priority)
__global__ void k_gather_sorted(const int* __restrict__ pay, const int* __restrict__ ei,
                                int* __restrict__ ss, int* __restrict__ dd,
                                unsigned long long* __restrict__ wl,
                                unsigned char* __restrict__ take) {
  int i = blockIdx.x * blockDim.x + threadIdx.x;
  if (i >= N_EDGES) return;
  int o = pay[i];
  int s = ei[o];
  int d = ei[N_EDGES + o];
  ss[i] = s;
  dd[i] = d;
  wl[i] = ((unsigned long long)i << 30) | ((unsigned long long)(unsigned)s << 15)
        | (unsigned long long)(unsigned)d;
  take[i] = 0;
}

// ---------- K16: persistent single-block EXACT sequential greedy matching ----------
// PIPELINED chunked design. Per iteration cc (one barrier each):
//   wave 0     : walks staged chunk cc-1 from buf[(cc-1)&1]  (exact greedy order)
//   waves 1..15: stage chunk cc into buf[cc&1] -- each wave owns one 256-edge
//     REGION: global load, alive-check vs (possibly stale) avail, intra-wave
//     order-preserving compaction, then per-group kill-masks via READLANE
//     broadcast (no LDS inner loop).
// Staleness is safe: avail is monotone 1->0, so stale staging keeps a SUPERSET
// of truly-alive edges; the walk re-checks avail. Kill-masks are structural
// (depend only on endpoint pairs). => take-set == sequential greedy, outputs
// bit-identical. Walk take loop: j=ffs(am); am&=~readlane(km,j) (~30cy/take).
__global__ __launch_bounds__(1024) void k_match(const unsigned long long* __restrict__ wl,
                                                unsigned char* __restrict__ take,
                                                int* __restrict__ g_avail) {
  __shared__ unsigned char avail[N_NODES];           // 20000 B
  __shared__ unsigned long long comp[2][CH];         // 61440 B
  __shared__ unsigned long long kmask[2][CH];        // 61440 B
  __shared__ unsigned rcnt[2][16];                   // 128 B
  int t = threadIdx.x;
  int lane = t & 63, wid = t >> 6;
  unsigned long long lmask_lt = (lane == 0) ? 0ull : (~0ull >> (64 - lane));
  for (int n = t; n < N_NODES; n += 1024) avail[n] = 1;
  __syncthreads();
  for (int cc = 0; cc <= NCH; ++cc) {
    // ---- stagers: stage chunk cc into buf[cc&1]
    if (wid >= 1 && cc < NCH) {
      int nb = cc & 1;
      int r = wid - 1;
      int ebase = cc * CH + r * REG;
      int rb = r * REG;
      int rc = 0;
      for (int g4 = 0; g4 < REG / 64; ++g4) {
        int i = ebase + g4 * 64 + lane;
        unsigned long long v = (i < N_EDGES) ? wl[i] : 0ull;
        bool a = false;
        if (i < N_EDGES) {
          int d = (int)(v & 0x7FFFu);
          int s = (int)((v >> 15) & 0x7FFFu);
          a = avail[s] && avail[d];   // stale-ok (superset)
        }
        unsigned long long bal = __ballot(a);
        if (a) {
          int rank = (int)__popcll(bal & lmask_lt);
          comp[nb][rb + rc + rank] = v;
        }
        rc += (int)__popcll(bal);
      }
      if (lane == 0) rcnt[nb][r] = (unsigned)rc;
      // kill-masks per compacted group, readlane-broadcast (no LDS inner loop)
      int ng = (rc + 63) >> 6;
      for (int g = 0; g < ng; ++g) {
        int glen = rc - g * 64; if (glen > 64) glen = 64;
        int lc = (lane < glen) ? lane : (glen - 1);
        unsigned long long v = comp[nb][rb + g * 64 + lc];
        int d = (int)(v & 0x7FFFu);
        int s = (int)((v >> 15) & 0x7FFFu);
        unsigned long long km = 1ull << lane;   // self bit
        for (int j = 1; j < glen; ++j) {
          int sj = __builtin_amdgcn_readlane(s, j);
          int dj = __builtin_amdgcn_readlane(d, j);
          if (lane < j && (s == sj || s == dj || d == sj || d == dj))
            km |= 1ull << j;
        }
        kmask[nb][rb + g * 64 + lane] = km;
      }
    }
    // ---- wave 0: walk staged chunk cc-1 from buf[(cc-1)&1]
    if (wid == 0 && cc >= 1) {
      int cb = (cc - 1) & 1;
      int rcv = (lane < NREG) ? (int)rcnt[cb][lane] : 0;
      for (int r = 0; r < NREG; ++r) {
        int rc = __shfl(rcv, r);
        if (rc == 0) continue;
        int rb = r * REG;
        int ng = (rc + 63) >> 6;
        for (int g = 0; g < ng; ++g) {
          int glen = rc - g * 64; if (glen > 64) glen = 64;
          int lc = (lane < glen) ? lane : (glen - 1);
          unsigned long long v = comp[cb][rb + g * 64 + lc];
          unsigned long long km = kmask[cb][rb + g * 64 + lc];
          unsigned km_lo = (unsigned)km;
          unsigned km_hi = (unsigned)(km >> 32);
          int d = (int)(v & 0x7FFFu);
          int s = (int)((v >> 15) & 0x7FFFu);
          bool alive = (lane < glen) && avail[s] && avail[d];
          unsigned long long am = __ballot(alive);
          unsigned long long tk = 0;
          while (am) {
            int j = __ffsll((long long)am) - 1;
            tk |= 1ull << j;
            unsigned long long kj =
                ((unsigned long long)(unsigned)__builtin_amdgcn_readlane((int)km_hi, j) << 32)
              | (unsigned long long)(unsigned)__builtin_amdgcn_readlane((int)km_lo, j);
            am &= ~kj;
          }
          if ((tk >> lane) & 1ull) {
            take[(unsigned)(v >> 30)] = 1;
            avail[s] = 0; avail[d] = 0;
          }
        }
      }
    }
    __syncthreads();
  }
  for (int n = t; n < N_NODES; n += 1024) g_avail[n] = avail[n];
}

// ---------- K17/K17b: partial sums ----------
__global__ void k_take_part(const unsigned char* __restrict__ take, unsigned* __restrict__ tpart) {
  __shared__ unsigned s[256];
  int t = threadIdx.x; int base = blockIdx.x * BE;
  unsigned c = 0;
  for (int j = t; j < BE; j += 256) { int idx = base + j; if (idx < N_EDGES) c += take[idx]; }
  s[t] = c; __syncthreads();
  for (int off = 128; off > 0; off >>= 1) { if (t < off) s[t] += s[t + off]; __syncthreads(); }
  if (t == 0) tpart[blockIdx.x] = s[0];
}

__global__ void k_avail_part(const int* __restrict__ g_avail, unsigned* __restrict__ apart) {
  __shared__ unsigned s[256];
  int t = threadIdx.x; int base = blockIdx.x * BE;
  unsigned c = 0;
  for (int j = t; j < BE; j += 256) { int idx = base + j; if (idx < N_NODES) c += (unsigned)g_avail[idx]; }
  s[t] = c; __syncthreads();
  for (int off = 128; off > 0; off >>= 1) { if (t < off) s[t] += s[t + off]; __syncthreads(); }
  if (t == 0) apart[blockIdx.x] = s[0];
}

// ---------- K18: scan partials, compute n_matched / num_clusters ----------
__global__ void k_scan_parts(unsigned* __restrict__ tpart, unsigned* __restrict__ apart,
                             int* __restrict__ scal) {
  __shared__ unsigned arr[512];
  int t = threadIdx.x;   // 512 threads
  unsigned v = (t < NBLK) ? tpart[t] : 0u;
  arr[t] = v;
  __syncthreads();
  for (int off = 1; off < 512; off <<= 1) {
    unsigned u2 = (t >= off) ? arr[t - off] : 0u;
    __syncthreads();
    arr[t] += u2;
    __syncthreads();
  }
  unsigned excl = arr[t] - v;
  if (t < NBLK) tpart[t] = excl;
  unsigned nm = arr[511];
  __syncthreads();
  if (t == 0) {
    unsigned run = 0;
    for (int b = 0; b < NBN; ++b) { unsigned tmp = apart[b]; apart[b] = run; run += tmp; }
    scal[0] = (int)nm;            // n_matched
    scal[2] = (int)run;           // n singleton
    scal[1] = (int)(nm + run);    // num_clusters
  }
}

// ---------- K19: assign ids to matched clusters ----------
__global__ void k_finalize_taken(const unsigned char* __restrict__ take, const int* __restrict__ pay,
                                 const int* __restrict__ ss, const int* __restrict__ dd,
                                 const float* __restrict__ e, const unsigned* __restrict__ tpart,
                                 int* __restrict__ cluster, int* __restrict__ clu,
                                 int* __restrict__ clv, float* __restrict__ csc) {
  __shared__ unsigned arr[256];
  int t = threadIdx.x; int b = blockIdx.x;
  int base = b * BE + t * 4;
  unsigned char tk[4];
  unsigned c = 0;
  for (int j = 0; j < 4; ++j) {
    int p = base + j;
    tk[j] = (p < N_EDGES) ? take[p] : (unsigned char)0;
    c += tk[j];
  }
  arr[t] = c;
  __syncthreads();
  unsigned v = c;
  for (int off = 1; off < 256; off <<= 1) {
    unsigned u2 = (t >= off) ? arr[t - off] : 0u;
    __syncthreads();
    arr[t] += u2;
    __syncthreads();
  }
  unsigned id = tpart[b] + (arr[t] - v);
  for (int j = 0; j < 4; ++j) {
    int p = base + j;
    if (p < N_EDGES && tk[j]) {
      int s = ss[p], d = dd[p];
      int u = min(s, d), w = max(s, d);
      cluster[s] = (int)id; cluster[d] = (int)id;
      clu[id] = u; clv[id] = w;
      csc[id] = e[pay[p]];
      ++id;
    }
  }
}

// ---------- K19b: singleton clusters ----------
__global__ void k_finalize_single(const int* __restrict__ g_avail, const unsigned* __restrict__ apart,
                                  const int* __restrict__ scal, int* __restrict__ cluster,
                                  int* __restrict__ clu, int* __restrict__ clv,
                                  float* __restrict__ csc) {
  __shared__ unsigned arr[256];
  int t = threadIdx.x; int b = blockIdx.x;
  int base = b * BE + t * 4;
  unsigned char av[4];
  unsigned c = 0;
  for (int j = 0; j < 4; ++j) {
    int n = base + j;
    av[j] = (n < N_NODES) ? (unsigned char)g_avail[n] : (unsigned char)0;
    c += av[j];
  }
  arr[t] = c;
  __syncthreads();
  unsigned v = c;
  for (int off = 1; off < 256; off <<= 1) {
    unsigned u2 = (t >= off) ? arr[t - off] : 0u;
    __syncthreads();
    arr[t] += u2;
    __syncthreads();
  }
  unsigned id = (unsigned)scal[0] + apart[b] + (arr[t] - v);
  for (int j = 0; j < 4; ++j) {
    int n = base + j;
    if (n < N_NODES && av[j]) {
      cluster[n] = (int)id;
      clu[id] = n; clv[id] = n;
      csc[id] = 1.0f;
      ++id;
    }
  }
}

// ---------- outputs ----------
__global__ void k_out_x(const float* __restrict__ x, const int* __restrict__ clu,
                        const int* __restrict__ clv, const float* __restrict__ csc,
                        const int* __restrict__ scal, float* __restrict__ out) {
  int c = blockIdx.x; int t = threadIdx.x;
  int nc = scal[1];
  float v = 0.f;
  if (c < nc) {
    int u = clu[c], w = clv[c];
    float a = x[(size_t)u * CDIM + t];
    if (w != u) a = __fadd_rn(a, x[(size_t)w * CDIM + t]);
    v = __fmul_rn(a, csc[c]);
  }
  out[OFF_X + (size_t)c * CDIM + t] = v;
}

__global__ void k_out_edges(const int* __restrict__ ei, const int* __restrict__ cluster,
                            float* __restrict__ out) {
  int i = blockIdx.x * blockDim.x + threadIdx.x;
  if (i < 2 * N_EDGES) out[OFF_EI + i] = (float)cluster[ei[i]];
}

__global__ void k_out_rest(const int* __restrict__ cluster, const int* __restrict__ clv,
                           const int* __restrict__ batch, const int* __restrict__ scal,
                           float* __restrict__ out) {
  int i = blockIdx.x * blockDim.x + threadIdx.x;
  if (i >= N_NODES) return;
  int nc = scal[1];
  out[OFF_CL + i] = (float)cluster[i];
  out[OFF_B + i] = (i < nc) ? (float)batch[clv[i]] : 0.0f;
  if (i == 0) out[OFF_NC] = (float)nc;
}

extern "C" void kernel_launch(void* const* d_in, const int* in_sizes, int n_in,
                              void* d_out, int out_size, void* d_ws, size_t ws_size,
                              hipStream_t stream) {
  const float* x     = (const float*)d_in[0];
  const int*   ei    = (const int*)d_in[1];
  const int*   batch = (const int*)d_in[2];
  const float* lw    = (const float*)d_in[3];
  const float* lb    = (const float*)d_in[4];
  float* out = (float*)d_out;

  int* w = (int*)d_ws;
  size_t off = 0;
  auto alloc = [&](size_t n) { int* p = w + off; off += n; return p; };
  float*    p1    = (float*)alloc(N_NODES);
  float*    p2    = (float*)alloc(N_NODES);
  float*    e     = (float*)alloc(N_EDGES);
  unsigned* keyA  = (unsigned*)alloc(N_EDGES);
  unsigned* keyB  = (unsigned*)alloc(N_EDGES);
  int*      payA  = (int*)alloc(N_EDGES);
  int*      payB  = (int*)alloc(N_EDGES);
  unsigned* hist  = (unsigned*)alloc(256 * NBLK);
  off = (off + 1) & ~(size_t)1;   // align to 8B for uint64 worklist
  unsigned long long* wl = (unsigned long long*)alloc(2 * N_EDGES);
  unsigned char* take = (unsigned char*)alloc(N_EDGES / 4);
  int*      cluster = (int*)alloc(N_NODES);
  int*      clu   = (int*)alloc(N_NODES);
  int*      clv   = (int*)alloc(N_NODES);
  float*    csc   = (float*)alloc(N_NODES);
  int*      g_avail = (int*)alloc(N_NODES);
  unsigned* tpart = (unsigned*)alloc(NBLK + 1);
  unsigned* apart = (unsigned*)alloc(NBN + 1);
  int*      scal  = (int*)alloc(16);
  // after the sort finishes in (keyA,payA), keyB/payB are dead -> reuse for sorted endpoints
  int* ss = (int*)keyB;
  int* dd = payB;

  // scores
  k_node_dots<<<(N_NODES + 255) / 256, 256, 0, stream>>>(x, lw, p1, p2);
  k_edge_scores<<<(N_EDGES + 255) / 256, 256, 0, stream>>>(ei, p1, p2, lb, e, keyA, payA);

  // stable LSD radix sort, 4 passes: A->B->A->B->A
  for (int pass = 0; pass < 4; ++pass) {
    int shift = pass * 8;
    const unsigned* ki = (pass & 1) ? keyB : keyA;
    unsigned*       ko = (pass & 1) ? keyA : keyB;
    const int*      pi = (pass & 1) ? payB : payA;
    int*            po = (pass & 1) ? payA : payB;
    k_radix_hist<<<NBLK, 256, 0, stream>>>(ki, N_EDGES, shift, hist);
    k_radix_scan<<<1, 256, 0, stream>>>(hist);
    k_radix_scatter<<<NBLK, 256, 0, stream>>>(ki, pi, N_EDGES, shift, hist, ko, po);
  }

  k_gather_sorted<<<(N_EDGES + 255) / 256, 256, 0, stream>>>(payA, ei, ss, dd, wl, take);
  k_match<<<1, 1024, 0, stream>>>(wl, take, g_avail);

  k_take_part<<<NBLK, 256, 0, stream>>>(take, tpart);
  k_avail_part<<<NBN, 256, 0, stream>>>(g_avail, apart);
  k_scan_parts<<<1, 512, 0, stream>>>(tpart, apart, scal);
  k_finalize_taken<<<NBLK, 256, 0, stream>>>(take, payA, ss, dd, e, tpart, cluster, clu, clv, csc);
  k_finalize_single<<<NBN, 256, 0, stream>>>(g_avail, apart, scal, cluster, clu, clv, csc);

  k_out_x<<<N_NODES, CDIM, 0, stream>>>(x, clu, clv, csc, scal, out);
  k_out_edges<<<(2 * N_EDGES + 255) / 256, 256, 0, stream>>>(ei, cluster, out);
  k_out_rest<<<(N_NODES + 255) / 256, 256, 0, stream>>>(cluster, clv, batch, scal, out);
}